// Round 8
// baseline (1956.467 us; speedup 1.0000x reference)
//
#include <hip/hip_runtime.h>

#define INF_F 3.402823466e+38f
typedef unsigned long long u64;
typedef __attribute__((ext_vector_type(2))) float f32x2;

__device__ __forceinline__ float f_add(float a, float b){ return __fadd_rn(a,b); }
__device__ __forceinline__ float f_sub(float a, float b){ return __fsub_rn(a,b); }
__device__ __forceinline__ float f_mul(float a, float b){ return __fmul_rn(a,b); }

// Packed fp32 (VOP3P) — same RN rounding as scalar, 2 elems/instr.
__device__ __forceinline__ f32x2 pk_add(f32x2 a, f32x2 b){ f32x2 d; asm("v_pk_add_f32 %0, %1, %2" : "=v"(d) : "v"(a), "v"(b)); return d; }
__device__ __forceinline__ f32x2 pk_mul(f32x2 a, f32x2 b){ f32x2 d; asm("v_pk_mul_f32 %0, %1, %2" : "=v"(d) : "v"(a), "v"(b)); return d; }
__device__ __forceinline__ f32x2 pk_fma(f32x2 a, f32x2 b, f32x2 c){ f32x2 d; asm("v_pk_fma_f32 %0, %1, %2, %3" : "=v"(d) : "v"(a), "v"(b), "v"(c)); return d; }

// DPP cross-lane (pure VALU). 0xB1=xor1, 0x4E=xor2, 0x141=xor4, 0x140=xor8.
template<int CTRL>
__device__ __forceinline__ double dpp_d(double x) {
    u64 u = (u64)__double_as_longlong(x);
    int lo = __builtin_amdgcn_update_dpp(0, (int)(unsigned)u,        CTRL, 0xF, 0xF, true);
    int hi = __builtin_amdgcn_update_dpp(0, (int)(unsigned)(u>>32), CTRL, 0xF, 0xF, true);
    return __longlong_as_double((long long)(((u64)(unsigned)hi << 32) | (unsigned)lo));
}
template<int CTRL>
__device__ __forceinline__ float dpp_f(float x) {
    int r = __builtin_amdgcn_update_dpp(0, __float_as_int(x), CTRL, 0xF, 0xF, true);
    return __int_as_float(r);
}
__device__ __forceinline__ float swz16_f(float x) {
    return __int_as_float(__builtin_amdgcn_ds_swizzle(__float_as_int(x), 0x401F));
}
__device__ __forceinline__ double readlane_d(double x, int l) {
    u64 u = (u64)__double_as_longlong(x);
    int lo = __builtin_amdgcn_readlane((int)(unsigned)u,        l);
    int hi = __builtin_amdgcn_readlane((int)(unsigned)(u>>32), l);
    return __longlong_as_double((long long)(((u64)(unsigned)hi << 32) | (unsigned)lo));
}
__device__ __forceinline__ double pack_key(float nd, unsigned low) {
    return __longlong_as_double((long long)(((u64)__float_as_uint(nd) << 32) | (u64)low));
}

// wave-64 reduce: 4 xor-DPP stages (16-groups done), then readlane tree.
__device__ __forceinline__ double wave_max_key(double k) {
    k = fmax(k, dpp_d<0xB1>(k));
    k = fmax(k, dpp_d<0x4E>(k));
    k = fmax(k, dpp_d<0x141>(k));
    k = fmax(k, dpp_d<0x140>(k));
    double a = readlane_d(k, 0),  b = readlane_d(k, 16);
    double c = readlane_d(k, 32), d = readlane_d(k, 48);
    return fmax(fmax(a, b), fmax(c, d));
}
__device__ __forceinline__ double wave_min_key(double k) {
    k = fmin(k, dpp_d<0xB1>(k));
    k = fmin(k, dpp_d<0x4E>(k));
    k = fmin(k, dpp_d<0x141>(k));
    k = fmin(k, dpp_d<0x140>(k));
    double a = readlane_d(k, 0),  b = readlane_d(k, 16);
    double c = readlane_d(k, 32), d = readlane_d(k, 48);
    return fmin(fmin(a, b), fmin(c, d));
}

// ---------------------------------------------------------------------------
// PRIMARY FPS: ONE wave per batch — zero barriers, zero cross-wave traffic.
// Each lane owns 64 points in registers (256 persistent VGPRs; bounds (64,1)
// allows 512). Per iter: update all 64 dists (packed fp32, exact RN, exact
// reference op order), fold keys into 8 chains, in-wave DPP+readlane reduce,
// one ds_read_b128 for the next centroid. Key = (bits(nd)<<32)|(4095-n):
// fmax == (value, lowest-index) == np.argmax. Same key set as prior rounds.
// ---------------------------------------------------------------------------
__global__ __launch_bounds__(64, 1) void fps1w_kernel(
    const float* __restrict__ xyz, const int* __restrict__ farthest_init,
    float* __restrict__ out_new_xyz)
{
    const int b    = blockIdx.x;
    const int lane = threadIdx.x;

    __shared__ float4 sp[4096];
    __shared__ int    hist[1024];

    const float* xb = xyz + (size_t)b * 4096 * 3;
    for (int n = lane; n < 4096; n += 64)
        sp[n] = make_float4(xb[n*3+0], xb[n*3+1], xb[n*3+2], 0.0f);
    __syncthreads();

    f32x2 px[32], py[32], pz[32], d2a[32];
    #pragma unroll
    for (int jp = 0; jp < 32; ++jp) {
        const int n0 = (2*jp)*64 + lane, n1 = n0 + 64;
        float4 a = sp[n0], c = sp[n1];
        px[jp] = (f32x2){a.x, c.x};
        py[jp] = (f32x2){a.y, c.y};
        pz[jp] = (f32x2){a.z, c.z};
        d2a[jp] = (f32x2){1e10f, 1e10f};
    }
    const unsigned lowbase = 4095u - (unsigned)lane;

    int far = farthest_init[b];
    float4 cen = sp[far];
    float cx = cen.x, cy = cen.y, cz = cen.z;

    #pragma unroll 1
    for (int it = 0; it < 1024; ++it) {
        if (lane == 0) hist[it] = far;
        const f32x2 ncx = (f32x2){-cx, -cx};
        const f32x2 ncy = (f32x2){-cy, -cy};
        const f32x2 ncz = (f32x2){-cz, -cz};

        double acc[8];
        #pragma unroll
        for (int i = 0; i < 8; ++i) acc[i] = -1.0;

        #pragma unroll
        for (int jp = 0; jp < 32; ++jp) {          // constant indices only (unrolled)
            f32x2 dx = pk_add(px[jp], ncx);        // x + (-c) == x - c exactly
            f32x2 dy = pk_add(py[jp], ncy);
            f32x2 dz = pk_add(pz[jp], ncz);
            // exact reference order: (dx^2 + dy^2) + dz^2, no FMA
            f32x2 d2 = pk_add(pk_add(pk_mul(dx,dx), pk_mul(dy,dy)), pk_mul(dz,dz));
            float nd0 = fminf(d2a[jp][0], d2[0]); d2a[jp][0] = nd0;
            float nd1 = fminf(d2a[jp][1], d2[1]); d2a[jp][1] = nd1;
            double k0 = pack_key(nd0, lowbase - (unsigned)((2*jp)*64));
            double k1 = pack_key(nd1, lowbase - (unsigned)((2*jp+1)*64));
            acc[jp & 3]       = fmax(acc[jp & 3],       k0);
            acc[4 + (jp & 3)] = fmax(acc[4 + (jp & 3)], k1);
        }
        double best = fmax(fmax(fmax(acc[0], acc[1]), fmax(acc[2], acc[3])),
                           fmax(fmax(acc[4], acc[5]), fmax(acc[6], acc[7])));
        double g = wave_max_key(best);
        far = 4095 - (int)(unsigned)((u64)__double_as_longlong(g) & 0xFFFFFFFFull);
        float4 cc = sp[far];                        // single ds_read_b128
        cx = cc.x; cy = cc.y; cz = cc.z;
    }
    __syncthreads();
    #pragma unroll
    for (int q = 0; q < 16; ++q) {
        int s = q * 64 + lane;
        float4 cc = sp[hist[s]];
        float* o = out_new_xyz + ((size_t)b * 1024 + s) * 3;
        o[0] = cc.x; o[1] = cc.y; o[2] = cc.z;
    }
}

// ---------------------------------------------------------------------------
// DIAGNOSTIC: the 4-wave r7 skeleton with the distance update REMOVED.
// Measures the pure communication floor: DPP reduce -> slot write -> barrier
// -> slot read -> fold -> sp[far] LDS read, kept live via an LCG whose state
// mixes in the fold result and centroid bits (not hoistable/DCE-able).
// Writes to scratch only.
// ---------------------------------------------------------------------------
__global__ __launch_bounds__(256, 1) void fps_skel_kernel(
    const float* __restrict__ xyz, const int* __restrict__ farthest_init,
    unsigned* __restrict__ dbg)
{
    const int b    = blockIdx.x;
    const int tid  = threadIdx.x;
    const int lane = tid & 63;
    const int wid  = tid >> 6;

    __shared__ float4 sp[4096];
    __shared__ double red[2][4];

    const float* xb = xyz + (size_t)b * 4096 * 3;
    for (int n = tid; n < 4096; n += 256)
        sp[n] = make_float4(xb[n*3+0], xb[n*3+1], xb[n*3+2], 0.0f);
    __syncthreads();

    unsigned seed = 12345u + (unsigned)tid;
    int far = farthest_init[b];
    float cx = sp[far].x;
    int p = 0;
    #pragma unroll 1
    for (int it = 0; it < 1024; ++it) {
        unsigned mix = seed ^ (__float_as_uint(cx) & 1023u);
        double k0 = pack_key(1e10f, 4095u - (mix & 4095u));
        double wkey = wave_max_key(k0);
        if (lane == 0) red[p][wid] = wkey;
        __syncthreads();
        double g = fmax(fmax(red[p][0], red[p][1]), fmax(red[p][2], red[p][3]));
        unsigned lowb = (unsigned)((u64)__double_as_longlong(g) & 0xFFFFFFFFull);
        seed = seed * 1664525u + 1013904223u + lowb;
        far = (int)(lowb & 4095u);
        float4 cc = sp[far];
        cx = cc.x;
        p ^= 1;
    }
    if (tid == 0) dbg[b] = seed ^ __float_as_uint(cx);
}

// ---------------------------------------------------------------------------
// Kernel 2: kNN top-32 (unchanged). One wave per centroid.
// ---------------------------------------------------------------------------
template<int G>
__device__ __forceinline__ double rebuild8(const double (&key)[64], double w) {
    const double DINF = __builtin_huge_val();
    double m = DINF;
    #pragma unroll
    for (int e = 0; e < 8; ++e) {
        double v = key[G*8+e];
        v = (v > w) ? v : DINF;
        m = fmin(m, v);
    }
    return m;
}

__global__ __launch_bounds__(256, 1) void knn_kernel(
    const float* __restrict__ xyz, const float* __restrict__ new_xyz,
    int* __restrict__ out_idx)
{
    const int tid  = threadIdx.x;
    const int lane = tid & 63;
    const int wid  = tid >> 6;
    const int blk  = blockIdx.x * 4 + wid;   // 0..8191 = b*1024 + s
    const int b    = blk >> 10;

    const float* xb = xyz + (size_t)b * 4096 * 3;
    const float* cp = new_xyz + (size_t)blk * 3;
    const float cx = cp[0], cy = cp[1], cz = cp[2];
    const float src2 = f_add(f_add(f_mul(cx,cx), f_mul(cy,cy)), f_mul(cz,cz));

    double key[64];
    #pragma unroll
    for (int j = 0; j < 64; ++j) {
        const int n = j * 64 + lane;
        const float* pt = xb + n * 3;
        float x = pt[0], y = pt[1], z = pt[2];
        float dst2 = f_add(f_add(f_mul(x,x), f_mul(y,y)), f_mul(z,z));
        float dot  = f_add(f_add(f_mul(cx,x), f_mul(cy,y)), f_mul(cz,z));
        float d = f_sub(f_add(src2, dst2), f_mul(2.0f, dot));   // exact reference form
        key[j] = __longlong_as_double((long long)(((u64)__float_as_uint(d) << 32) | (u64)(unsigned)n));
    }

    double gm[8];
    #pragma unroll
    for (int g = 0; g < 8; ++g) {
        double m = key[g*8];
        #pragma unroll
        for (int e = 1; e < 8; ++e) m = fmin(m, key[g*8+e]);
        gm[g] = m;
    }

    double w = -1.0;
    int myidx = 0;
    #pragma unroll 1
    for (int t = 0; t < 32; ++t) {
        double lm = fmin(fmin(fmin(gm[0], gm[1]), fmin(gm[2], gm[3])),
                         fmin(fmin(gm[4], gm[5]), fmin(gm[6], gm[7])));
        double gmin = wave_min_key(lm);
        int n = (int)(unsigned)((u64)__double_as_longlong(gmin) & 0xFFFFFFFFull);
        if (lane == t) myidx = n;
        w = gmin;
        const int gs = __builtin_amdgcn_readfirstlane(n >> 9);
        switch (gs) {
            case 0: gm[0] = rebuild8<0>(key, w); break;
            case 1: gm[1] = rebuild8<1>(key, w); break;
            case 2: gm[2] = rebuild8<2>(key, w); break;
            case 3: gm[3] = rebuild8<3>(key, w); break;
            case 4: gm[4] = rebuild8<4>(key, w); break;
            case 5: gm[5] = rebuild8<5>(key, w); break;
            case 6: gm[6] = rebuild8<6>(key, w); break;
            case 7: gm[7] = rebuild8<7>(key, w); break;
        }
    }
    if (lane < 32) out_idx[(size_t)blk * 32 + lane] = myidx;
}

// ---------------------------------------------------------------------------
// Kernel 3: 3-layer MLP + max-pool over K=32 (unchanged).
// ---------------------------------------------------------------------------
__global__ __launch_bounds__(256, 1) void mlp_kernel(
    const float* __restrict__ xyz, const float* __restrict__ points,
    const int* __restrict__ knn_idx,
    const float* __restrict__ w0, const float* __restrict__ b0,
    const float* __restrict__ w1, const float* __restrict__ b1,
    const float* __restrict__ w2, const float* __restrict__ b2,
    const float* __restrict__ new_xyz, float* __restrict__ out_np)
{
    const int tid = threadIdx.x;
    const int k   = tid & 31;
    const int gs  = blockIdx.x * 8 + (tid >> 5);   // 0..8191
    const int b   = gs >> 10;
    const int n   = knn_idx[(size_t)gs * 32 + k];

    const float cx = new_xyz[gs*3+0], cy = new_xyz[gs*3+1], cz = new_xyz[gs*3+2];
    const float* pxyz = xyz + ((size_t)b * 4096 + n) * 3;
    float h0[9];
    h0[0] = pxyz[0] - cx;
    h0[1] = pxyz[1] - cy;
    h0[2] = pxyz[2] - cz;
    const float* pp = points + ((size_t)b * 4096 + n) * 6;
    #pragma unroll
    for (int c = 0; c < 6; ++c) h0[3 + c] = pp[c];

    f32x2 h1p[32];
    #pragma unroll
    for (int o = 0; o < 64; o += 2) {
        float accA = b0[o], accB = b0[o+1];
        #pragma unroll
        for (int c = 0; c < 9; ++c) {
            accA = fmaf(h0[c], w0[o*9+c],     accA);
            accB = fmaf(h0[c], w0[(o+1)*9+c], accB);
        }
        h1p[o>>1] = (f32x2){fmaxf(accA, 0.0f), fmaxf(accB, 0.0f)};
    }

    const f32x2* w1v = (const f32x2*)w1;   // [64][32] pairs
    f32x2 h2p[32];
    #pragma unroll
    for (int o = 0; o < 64; o += 2) {
        f32x2 accA = (f32x2){b1[o],   0.0f};
        f32x2 accB = (f32x2){b1[o+1], 0.0f};
        #pragma unroll
        for (int i = 0; i < 32; ++i) {
            accA = pk_fma(h1p[i], w1v[o*32+i],     accA);
            accB = pk_fma(h1p[i], w1v[(o+1)*32+i], accB);
        }
        h2p[o>>1] = (f32x2){fmaxf(accA[0]+accA[1], 0.0f), fmaxf(accB[0]+accB[1], 0.0f)};
    }

    const f32x2* w2v = (const f32x2*)w2;   // [128][32] pairs
    float* outp = out_np + (size_t)gs * 128;
    for (int og = 0; og < 4; ++og) {
        float keep = 0.0f;
        for (int o2 = 0; o2 < 32; ++o2) {
            const int o = og * 32 + o2;
            f32x2 acc = (f32x2){b2[o], 0.0f};
            #pragma unroll
            for (int i = 0; i < 32; ++i) acc = pk_fma(h2p[i], w2v[o*32+i], acc);
            float m = fmaxf(acc[0] + acc[1], 0.0f);
            m = fmaxf(m, dpp_f<0xB1>(m));
            m = fmaxf(m, dpp_f<0x4E>(m));
            m = fmaxf(m, dpp_f<0x141>(m));
            m = fmaxf(m, dpp_f<0x140>(m));
            m = fmaxf(m, swz16_f(m));
            keep = (k == o2) ? m : keep;
        }
        outp[og * 32 + k] = keep;
    }
}

// ---------------------------------------------------------------------------
// Fallback (ws too small): fused kNN+MLP (known-correct).
// ---------------------------------------------------------------------------
__global__ __launch_bounds__(256) void knn_mlp_kernel(
    const float* __restrict__ xyz, const float* __restrict__ points,
    const float* __restrict__ w0, const float* __restrict__ b0,
    const float* __restrict__ w1, const float* __restrict__ b1,
    const float* __restrict__ w2, const float* __restrict__ b2,
    const float* __restrict__ new_xyz, float* __restrict__ out_np)
{
    const int blk    = blockIdx.x;
    const int b      = blk >> 7;
    const int s_base = (blk & 127) * 8;
    const int tid    = threadIdx.x;
    const int lane   = tid & 63;
    const int wid    = tid >> 6;

    __shared__ float sx[4096], sy[4096], sz[4096];
    __shared__ float cent[8][3];
    __shared__ int   idxbuf[8][32];

    const float* xb = xyz + (size_t)b * 4096 * 3;
    for (int n = tid; n < 4096; n += 256) {
        sx[n] = xb[n*3+0]; sy[n] = xb[n*3+1]; sz[n] = xb[n*3+2];
    }
    if (tid < 24) ((float*)cent)[tid] = new_xyz[((size_t)b * 1024 + s_base) * 3 + tid];
    __syncthreads();

    for (int si = 0; si < 2; ++si) {
        const int sl = wid * 2 + si;
        const float cx = cent[sl][0], cy = cent[sl][1], cz = cent[sl][2];
        const float src2 = f_add(f_add(f_mul(cx,cx), f_mul(cy,cy)), f_mul(cz,cz));
        float d[64];
        #pragma unroll
        for (int j = 0; j < 64; ++j) {
            int n = j * 64 + lane;
            float x = sx[n], y = sy[n], z = sz[n];
            float dst2 = f_add(f_add(f_mul(x,x), f_mul(y,y)), f_mul(z,z));
            float dot  = f_add(f_add(f_mul(cx,x), f_mul(cy,y)), f_mul(cz,z));
            d[j] = f_sub(f_add(src2, dst2), f_mul(2.0f, dot));
        }
        int myg  = 0;
        int prev = -1;
        for (int t = 0; t < 32; ++t) {
            float bv = INF_F; int bi = 0x7fffffff;
            #pragma unroll
            for (int j = 0; j < 64; ++j) {
                int n = j * 64 + lane;
                if (n == prev) d[j] = INF_F;
                float v = d[j];
                if (v < bv) { bv = v; bi = n; }
            }
            #pragma unroll
            for (int m = 1; m < 64; m <<= 1) {
                float ov = __shfl_xor(bv, m);
                int   oi = __shfl_xor(bi, m);
                if (ov < bv || (ov == bv && oi < bi)) { bv = ov; bi = oi; }
            }
            if (lane == t) myg = bi;
            prev = bi;
        }
        if (lane < 32) idxbuf[sl][lane] = myg;
    }
    __syncthreads();

    const int k   = tid & 31;
    const int sl2 = tid >> 5;
    const int s   = s_base + sl2;
    const int n   = idxbuf[sl2][k];

    const float cx = cent[sl2][0], cy = cent[sl2][1], cz = cent[sl2][2];
    float h0[9];
    h0[0] = sx[n] - cx;
    h0[1] = sy[n] - cy;
    h0[2] = sz[n] - cz;
    const float* pp = points + ((size_t)b * 4096 + n) * 6;
    #pragma unroll
    for (int c = 0; c < 6; ++c) h0[3 + c] = pp[c];

    float h1[64];
    #pragma unroll
    for (int o = 0; o < 64; ++o) {
        float acc = b0[o];
        #pragma unroll
        for (int c = 0; c < 9; ++c) acc = fmaf(h0[c], w0[o*9+c], acc);
        h1[o] = fmaxf(acc, 0.0f);
    }
    float h2[64];
    #pragma unroll
    for (int o = 0; o < 64; ++o) {
        float acc = b1[o];
        #pragma unroll
        for (int c = 0; c < 64; ++c) acc = fmaf(h1[c], w1[o*64+c], acc);
        h2[o] = fmaxf(acc, 0.0f);
    }
    float* outp = out_np + ((size_t)b * 1024 + s) * 128;
    for (int og = 0; og < 4; ++og) {
        float keep = 0.0f;
        for (int o2 = 0; o2 < 32; ++o2) {
            const int o = og * 32 + o2;
            float acc = b2[o];
            #pragma unroll
            for (int c = 0; c < 64; ++c) acc = fmaf(h2[c], w2[o*64+c], acc);
            float m = fmaxf(acc, 0.0f);
            #pragma unroll
            for (int mm = 1; mm < 32; mm <<= 1)
                m = fmaxf(m, __shfl_xor(m, mm));
            keep = (k == o2) ? m : keep;
        }
        outp[og * 32 + k] = keep;
    }
}

extern "C" void kernel_launch(void* const* d_in, const int* in_sizes, int n_in,
                              void* d_out, int out_size, void* d_ws, size_t ws_size,
                              hipStream_t stream) {
    const float* xyz           = (const float*)d_in[0];
    const float* points        = (const float*)d_in[1];
    const int*   farthest_init = (const int*)  d_in[2];
    const float* w0 = (const float*)d_in[3];
    const float* b0 = (const float*)d_in[4];
    const float* w1 = (const float*)d_in[5];
    const float* b1 = (const float*)d_in[6];
    const float* w2 = (const float*)d_in[7];
    const float* b2 = (const float*)d_in[8];

    float* out        = (float*)d_out;
    float* new_xyz    = out;                 // [8,1024,3]
    float* new_points = out + 8 * 1024 * 3;  // [8,1024,128]

    fps1w_kernel<<<8, 64, 0, stream>>>(xyz, farthest_init, new_xyz);

    if (ws_size >= (size_t)(8192 * 32 * sizeof(int))) {
        int* knn_idx = (int*)d_ws;
        knn_kernel<<<2048, 256, 0, stream>>>(xyz, new_xyz, knn_idx);
        mlp_kernel<<<1024, 256, 0, stream>>>(xyz, points, knn_idx,
                                             w0, b0, w1, b1, w2, b2,
                                             new_xyz, new_points);
    } else {
        knn_mlp_kernel<<<1024, 256, 0, stream>>>(xyz, points, w0, b0, w1, b1, w2, b2,
                                                 new_xyz, new_points);
    }

    // diagnostic dispatch (scratch-only): measures the 4-wave comm skeleton
    if (ws_size >= (size_t)(1 << 20) + 64) {
        unsigned* dbg = (unsigned*)((char*)d_ws + (1 << 20));
        fps_skel_kernel<<<8, 256, 0, stream>>>(xyz, farthest_init, dbg);
    }
}

// Round 9
// 1429.079 us; speedup vs baseline: 1.3690x; 1.3690x over previous
//
#include <hip/hip_runtime.h>

#define INF_F 3.402823466e+38f
typedef unsigned long long u64;
typedef __attribute__((ext_vector_type(2))) float f32x2;

__device__ __forceinline__ float f_add(float a, float b){ return __fadd_rn(a,b); }
__device__ __forceinline__ float f_sub(float a, float b){ return __fsub_rn(a,b); }
__device__ __forceinline__ float f_mul(float a, float b){ return __fmul_rn(a,b); }

// Packed fp32 (VOP3P) — same RN rounding as scalar, 2 elems/instr.
__device__ __forceinline__ f32x2 pk_add(f32x2 a, f32x2 b){ f32x2 d; asm("v_pk_add_f32 %0, %1, %2" : "=v"(d) : "v"(a), "v"(b)); return d; }
__device__ __forceinline__ f32x2 pk_mul(f32x2 a, f32x2 b){ f32x2 d; asm("v_pk_mul_f32 %0, %1, %2" : "=v"(d) : "v"(a), "v"(b)); return d; }
__device__ __forceinline__ f32x2 pk_fma(f32x2 a, f32x2 b, f32x2 c){ f32x2 d; asm("v_pk_fma_f32 %0, %1, %2, %3" : "=v"(d) : "v"(a), "v"(b), "v"(c)); return d; }

// DPP cross-lane (pure VALU). 0xB1=xor1, 0x4E=xor2, 0x141=xor7(8grp), 0x140=xor15(16grp)
template<int CTRL>
__device__ __forceinline__ double dpp_d(double x) {
    u64 u = (u64)__double_as_longlong(x);
    int lo = __builtin_amdgcn_update_dpp(0, (int)(unsigned)u,        CTRL, 0xF, 0xF, true);
    int hi = __builtin_amdgcn_update_dpp(0, (int)(unsigned)(u>>32), CTRL, 0xF, 0xF, true);
    return __longlong_as_double((long long)(((u64)(unsigned)hi << 32) | (unsigned)lo));
}
template<int CTRL>
__device__ __forceinline__ float dpp_f(float x) {
    int r = __builtin_amdgcn_update_dpp(0, __float_as_int(x), CTRL, 0xF, 0xF, true);
    return __int_as_float(r);
}
__device__ __forceinline__ float swz16_f(float x) {
    return __int_as_float(__builtin_amdgcn_ds_swizzle(__float_as_int(x), 0x401F));
}
__device__ __forceinline__ double readlane_d(double x, int l) {
    u64 u = (u64)__double_as_longlong(x);
    int lo = __builtin_amdgcn_readlane((int)(unsigned)u,        l);
    int hi = __builtin_amdgcn_readlane((int)(unsigned)(u>>32), l);
    return __longlong_as_double((long long)(((u64)(unsigned)hi << 32) | (unsigned)lo));
}
__device__ __forceinline__ float readlane_f(float x, int l) {
    return __int_as_float(__builtin_amdgcn_readlane(__float_as_int(x), l));
}
__device__ __forceinline__ unsigned key_lo(double k) {
    return (unsigned)((u64)__double_as_longlong(k) & 0xFFFFFFFFull);
}
__device__ __forceinline__ double pack_key(float nd, unsigned low) {
    return __longlong_as_double((long long)(((u64)__float_as_uint(nd) << 32) | (u64)low));
}

// wave-64 max of non-negative f64 keys -> all lanes (4 dpp stages + readlane tree)
__device__ __forceinline__ double wave_max_key(double k) {
    k = fmax(k, dpp_d<0xB1>(k));
    k = fmax(k, dpp_d<0x4E>(k));
    k = fmax(k, dpp_d<0x141>(k));
    k = fmax(k, dpp_d<0x140>(k));
    double a = readlane_d(k, 0),  b = readlane_d(k, 16);
    double c = readlane_d(k, 32), d = readlane_d(k, 48);
    return fmax(fmax(a, b), fmax(c, d));
}
__device__ __forceinline__ double wave_min_key(double k) {
    k = fmin(k, dpp_d<0xB1>(k));
    k = fmin(k, dpp_d<0x4E>(k));
    k = fmin(k, dpp_d<0x141>(k));
    k = fmin(k, dpp_d<0x140>(k));
    double a = readlane_d(k, 0),  b = readlane_d(k, 16);
    double c = readlane_d(k, 32), d = readlane_d(k, 48);
    return fmin(fmin(a, b), fmin(c, d));
}

// ---------------------------------------------------------------------------
// FPS, 16 waves (1024 threads) per batch. 4 points/thread -> update issue is
// ~16x smaller than r7's 4-wave version. The winning point's COORDS ride the
// reduction (branch-free cndmask select + readlane in-wave; DPP tuple reduce
// across the 16 wave-slots), eliminating the dependent sp[far] LDS read.
// Key = (bits(nd)<<32)|(4095-n) as f64: fmax == (val, lowest idx) == np.argmax.
// Key set identical to r7 -> FPS indices bit-exact.
// ---------------------------------------------------------------------------
__global__ __launch_bounds__(1024, 1) void fps16_kernel(
    const float* __restrict__ xyz, const int* __restrict__ farthest_init,
    float* __restrict__ out_new_xyz)
{
    const int b    = blockIdx.x;
    const int tid  = threadIdx.x;
    const int lane = tid & 63;
    const int wid  = tid >> 6;

    __shared__ float4 sp[4096];
    __shared__ int    hist[1024];
    __shared__ float4 slotA[2][16];   // {keylo, keyhi, x, y}
    __shared__ float  slotB[2][16];   // {z}

    const float* xb = xyz + (size_t)b * 4096 * 3;
    for (int n = tid; n < 4096; n += 1024)
        sp[n] = make_float4(xb[n*3+0], xb[n*3+1], xb[n*3+2], 0.0f);
    __syncthreads();

    // 4 points/thread: n = j*1024 + tid, packed as 2 f32x2 (j01, j23)
    f32x2 px[2], py[2], pz[2], d2a[2];
    #pragma unroll
    for (int jp = 0; jp < 2; ++jp) {
        const int n0 = (2*jp)*1024 + tid, n1 = n0 + 1024;
        float4 a = sp[n0], c = sp[n1];
        px[jp] = (f32x2){a.x, c.x};
        py[jp] = (f32x2){a.y, c.y};
        pz[jp] = (f32x2){a.z, c.z};
        d2a[jp] = (f32x2){1e10f, 1e10f};
    }
    const unsigned low0 = 4095u - (unsigned)tid;

    int far = farthest_init[b];
    float4 cen = sp[far];
    float cx = cen.x, cy = cen.y, cz = cen.z;
    int p = 0;

    #pragma unroll 1
    for (int it = 0; it < 1024; ++it) {
        if (tid == 0) hist[it] = far;
        const f32x2 ncx = (f32x2){-cx, -cx};
        const f32x2 ncy = (f32x2){-cy, -cy};
        const f32x2 ncz = (f32x2){-cz, -cz};

        // update 4 dists (exact RN, exact reference op order)
        f32x2 nd01, nd23;
        {
            f32x2 dx = pk_add(px[0], ncx);
            f32x2 dy = pk_add(py[0], ncy);
            f32x2 dz = pk_add(pz[0], ncz);
            f32x2 d2 = pk_add(pk_add(pk_mul(dx,dx), pk_mul(dy,dy)), pk_mul(dz,dz));
            nd01[0] = fminf(d2a[0][0], d2[0]);
            nd01[1] = fminf(d2a[0][1], d2[1]);
            d2a[0] = nd01;
        }
        {
            f32x2 dx = pk_add(px[1], ncx);
            f32x2 dy = pk_add(py[1], ncy);
            f32x2 dz = pk_add(pz[1], ncz);
            f32x2 d2 = pk_add(pk_add(pk_mul(dx,dx), pk_mul(dy,dy)), pk_mul(dz,dz));
            nd23[0] = fminf(d2a[1][0], d2[0]);
            nd23[1] = fminf(d2a[1][1], d2[1]);
            d2a[1] = nd23;
        }
        double k0 = pack_key(nd01[0], low0);
        double k1 = pack_key(nd01[1], low0 - 1024u);
        double k2 = pack_key(nd23[0], low0 - 2048u);
        double k3 = pack_key(nd23[1], low0 - 3072u);
        double best = fmax(fmax(k0, k1), fmax(k2, k3));

        // in-wave argmax, all lanes get wave winner key
        double wkey = wave_max_key(best);
        const int n_w = 4095 - (int)key_lo(wkey);
        const int jsel  = __builtin_amdgcn_readfirstlane(n_w >> 10);   // 0..3 uniform
        const int olane = __builtin_amdgcn_readfirstlane(n_w & 63);    // owner lane
        // branch-free coord select among this lane's 4 candidates
        f32x2 xa = (jsel & 2) ? px[1] : px[0];
        f32x2 ya = (jsel & 2) ? py[1] : py[0];
        f32x2 za = (jsel & 2) ? pz[1] : pz[0];
        float xs = (jsel & 1) ? xa[1] : xa[0];
        float ys = (jsel & 1) ? ya[1] : ya[0];
        float zs = (jsel & 1) ? za[1] : za[0];
        const float xw = readlane_f(xs, olane);
        const float yw = readlane_f(ys, olane);
        const float zw = readlane_f(zs, olane);

        if (lane == 0) {
            u64 kb = (u64)__double_as_longlong(wkey);
            slotA[p][wid] = make_float4(__uint_as_float((unsigned)kb),
                                        __uint_as_float((unsigned)(kb >> 32)), xw, yw);
            slotB[p][wid] = zw;
        }
        __syncthreads();

        // cross-wave: lanes<16 read slots, 4-stage DPP tuple reduce, bcast
        double kf; float xf, yf, zf;
        if (lane < 16) {
            float4 a = slotA[p][lane];
            kf = __longlong_as_double((long long)(
                     ((u64)__float_as_uint(a.y) << 32) | (u64)__float_as_uint(a.x)));
            xf = a.z; yf = a.w; zf = slotB[p][lane];
        } else {
            kf = -1.0; xf = 0.0f; yf = 0.0f; zf = 0.0f;
        }
        {
            double pk; float pxx, pyy, pzz; bool gt;
            pk = dpp_d<0xB1>(kf); pxx = dpp_f<0xB1>(xf); pyy = dpp_f<0xB1>(yf); pzz = dpp_f<0xB1>(zf);
            gt = pk > kf; kf = gt ? pk : kf; xf = gt ? pxx : xf; yf = gt ? pyy : yf; zf = gt ? pzz : zf;
            pk = dpp_d<0x4E>(kf); pxx = dpp_f<0x4E>(xf); pyy = dpp_f<0x4E>(yf); pzz = dpp_f<0x4E>(zf);
            gt = pk > kf; kf = gt ? pk : kf; xf = gt ? pxx : xf; yf = gt ? pyy : yf; zf = gt ? pzz : zf;
            pk = dpp_d<0x141>(kf); pxx = dpp_f<0x141>(xf); pyy = dpp_f<0x141>(yf); pzz = dpp_f<0x141>(zf);
            gt = pk > kf; kf = gt ? pk : kf; xf = gt ? pxx : xf; yf = gt ? pyy : yf; zf = gt ? pzz : zf;
            pk = dpp_d<0x140>(kf); pxx = dpp_f<0x140>(xf); pyy = dpp_f<0x140>(yf); pzz = dpp_f<0x140>(zf);
            gt = pk > kf; kf = gt ? pk : kf; xf = gt ? pxx : xf; yf = gt ? pyy : yf; zf = gt ? pzz : zf;
        }
        const double gkey = readlane_d(kf, 0);
        cx = readlane_f(xf, 0);
        cy = readlane_f(yf, 0);
        cz = readlane_f(zf, 0);
        far = 4095 - (int)key_lo(gkey);
        p ^= 1;   // double-buffered slots: 1 barrier per iteration
    }
    __syncthreads();
    {
        float4 cc = sp[hist[tid]];
        float* o = out_new_xyz + ((size_t)b * 1024 + tid) * 3;
        o[0] = cc.x; o[1] = cc.y; o[2] = cc.z;
    }
}

// ---------------------------------------------------------------------------
// Kernel 2: kNN top-32 (unchanged from r7). One wave per centroid.
// ---------------------------------------------------------------------------
template<int G>
__device__ __forceinline__ double rebuild8(const double (&key)[64], double w) {
    const double DINF = __builtin_huge_val();
    double m = DINF;
    #pragma unroll
    for (int e = 0; e < 8; ++e) {
        double v = key[G*8+e];
        v = (v > w) ? v : DINF;
        m = fmin(m, v);
    }
    return m;
}

__global__ __launch_bounds__(256, 1) void knn_kernel(
    const float* __restrict__ xyz, const float* __restrict__ new_xyz,
    int* __restrict__ out_idx)
{
    const int tid  = threadIdx.x;
    const int lane = tid & 63;
    const int wid  = tid >> 6;
    const int blk  = blockIdx.x * 4 + wid;   // 0..8191 = b*1024 + s
    const int b    = blk >> 10;

    const float* xb = xyz + (size_t)b * 4096 * 3;
    const float* cp = new_xyz + (size_t)blk * 3;
    const float cx = cp[0], cy = cp[1], cz = cp[2];
    const float src2 = f_add(f_add(f_mul(cx,cx), f_mul(cy,cy)), f_mul(cz,cz));

    double key[64];
    #pragma unroll
    for (int j = 0; j < 64; ++j) {
        const int n = j * 64 + lane;
        const float* pt = xb + n * 3;
        float x = pt[0], y = pt[1], z = pt[2];
        float dst2 = f_add(f_add(f_mul(x,x), f_mul(y,y)), f_mul(z,z));
        float dot  = f_add(f_add(f_mul(cx,x), f_mul(cy,y)), f_mul(cz,z));
        float d = f_sub(f_add(src2, dst2), f_mul(2.0f, dot));   // exact reference form
        key[j] = __longlong_as_double((long long)(((u64)__float_as_uint(d) << 32) | (u64)(unsigned)n));
    }

    double gm[8];
    #pragma unroll
    for (int g = 0; g < 8; ++g) {
        double m = key[g*8];
        #pragma unroll
        for (int e = 1; e < 8; ++e) m = fmin(m, key[g*8+e]);
        gm[g] = m;
    }

    double w = -1.0;
    int myidx = 0;
    #pragma unroll 1
    for (int t = 0; t < 32; ++t) {
        double lm = fmin(fmin(fmin(gm[0], gm[1]), fmin(gm[2], gm[3])),
                         fmin(fmin(gm[4], gm[5]), fmin(gm[6], gm[7])));
        double gmin = wave_min_key(lm);
        int n = (int)(unsigned)((u64)__double_as_longlong(gmin) & 0xFFFFFFFFull);
        if (lane == t) myidx = n;
        w = gmin;
        const int gs = __builtin_amdgcn_readfirstlane(n >> 9);
        switch (gs) {
            case 0: gm[0] = rebuild8<0>(key, w); break;
            case 1: gm[1] = rebuild8<1>(key, w); break;
            case 2: gm[2] = rebuild8<2>(key, w); break;
            case 3: gm[3] = rebuild8<3>(key, w); break;
            case 4: gm[4] = rebuild8<4>(key, w); break;
            case 5: gm[5] = rebuild8<5>(key, w); break;
            case 6: gm[6] = rebuild8<6>(key, w); break;
            case 7: gm[7] = rebuild8<7>(key, w); break;
        }
    }
    if (lane < 32) out_idx[(size_t)blk * 32 + lane] = myidx;
}

// ---------------------------------------------------------------------------
// Kernel 3: 3-layer MLP + max-pool over K=32 (unchanged from r7).
// ---------------------------------------------------------------------------
__global__ __launch_bounds__(256, 1) void mlp_kernel(
    const float* __restrict__ xyz, const float* __restrict__ points,
    const int* __restrict__ knn_idx,
    const float* __restrict__ w0, const float* __restrict__ b0,
    const float* __restrict__ w1, const float* __restrict__ b1,
    const float* __restrict__ w2, const float* __restrict__ b2,
    const float* __restrict__ new_xyz, float* __restrict__ out_np)
{
    const int tid = threadIdx.x;
    const int k   = tid & 31;
    const int gs  = blockIdx.x * 8 + (tid >> 5);   // 0..8191
    const int b   = gs >> 10;
    const int n   = knn_idx[(size_t)gs * 32 + k];

    const float cx = new_xyz[gs*3+0], cy = new_xyz[gs*3+1], cz = new_xyz[gs*3+2];
    const float* pxyz = xyz + ((size_t)b * 4096 + n) * 3;
    float h0[9];
    h0[0] = pxyz[0] - cx;
    h0[1] = pxyz[1] - cy;
    h0[2] = pxyz[2] - cz;
    const float* pp = points + ((size_t)b * 4096 + n) * 6;
    #pragma unroll
    for (int c = 0; c < 6; ++c) h0[3 + c] = pp[c];

    f32x2 h1p[32];
    #pragma unroll
    for (int o = 0; o < 64; o += 2) {
        float accA = b0[o], accB = b0[o+1];
        #pragma unroll
        for (int c = 0; c < 9; ++c) {
            accA = fmaf(h0[c], w0[o*9+c],     accA);
            accB = fmaf(h0[c], w0[(o+1)*9+c], accB);
        }
        h1p[o>>1] = (f32x2){fmaxf(accA, 0.0f), fmaxf(accB, 0.0f)};
    }

    const f32x2* w1v = (const f32x2*)w1;   // [64][32] pairs
    f32x2 h2p[32];
    #pragma unroll
    for (int o = 0; o < 64; o += 2) {
        f32x2 accA = (f32x2){b1[o],   0.0f};
        f32x2 accB = (f32x2){b1[o+1], 0.0f};
        #pragma unroll
        for (int i = 0; i < 32; ++i) {
            accA = pk_fma(h1p[i], w1v[o*32+i],     accA);
            accB = pk_fma(h1p[i], w1v[(o+1)*32+i], accB);
        }
        h2p[o>>1] = (f32x2){fmaxf(accA[0]+accA[1], 0.0f), fmaxf(accB[0]+accB[1], 0.0f)};
    }

    const f32x2* w2v = (const f32x2*)w2;   // [128][32] pairs
    float* outp = out_np + (size_t)gs * 128;
    for (int og = 0; og < 4; ++og) {
        float keep = 0.0f;
        for (int o2 = 0; o2 < 32; ++o2) {
            const int o = og * 32 + o2;
            f32x2 acc = (f32x2){b2[o], 0.0f};
            #pragma unroll
            for (int i = 0; i < 32; ++i) acc = pk_fma(h2p[i], w2v[o*32+i], acc);
            float m = fmaxf(acc[0] + acc[1], 0.0f);
            m = fmaxf(m, dpp_f<0xB1>(m));
            m = fmaxf(m, dpp_f<0x4E>(m));
            m = fmaxf(m, dpp_f<0x141>(m));
            m = fmaxf(m, dpp_f<0x140>(m));
            m = fmaxf(m, swz16_f(m));
            keep = (k == o2) ? m : keep;
        }
        outp[og * 32 + k] = keep;
    }
}

// ---------------------------------------------------------------------------
// Fallback (ws too small): fused kNN+MLP (known-correct).
// ---------------------------------------------------------------------------
__global__ __launch_bounds__(256) void knn_mlp_kernel(
    const float* __restrict__ xyz, const float* __restrict__ points,
    const float* __restrict__ w0, const float* __restrict__ b0,
    const float* __restrict__ w1, const float* __restrict__ b1,
    const float* __restrict__ w2, const float* __restrict__ b2,
    const float* __restrict__ new_xyz, float* __restrict__ out_np)
{
    const int blk    = blockIdx.x;
    const int b      = blk >> 7;
    const int s_base = (blk & 127) * 8;
    const int tid    = threadIdx.x;
    const int lane   = tid & 63;
    const int wid    = tid >> 6;

    __shared__ float sx[4096], sy[4096], sz[4096];
    __shared__ float cent[8][3];
    __shared__ int   idxbuf[8][32];

    const float* xb = xyz + (size_t)b * 4096 * 3;
    for (int n = tid; n < 4096; n += 256) {
        sx[n] = xb[n*3+0]; sy[n] = xb[n*3+1]; sz[n] = xb[n*3+2];
    }
    if (tid < 24) ((float*)cent)[tid] = new_xyz[((size_t)b * 1024 + s_base) * 3 + tid];
    __syncthreads();

    for (int si = 0; si < 2; ++si) {
        const int sl = wid * 2 + si;
        const float cx = cent[sl][0], cy = cent[sl][1], cz = cent[sl][2];
        const float src2 = f_add(f_add(f_mul(cx,cx), f_mul(cy,cy)), f_mul(cz,cz));
        float d[64];
        #pragma unroll
        for (int j = 0; j < 64; ++j) {
            int n = j * 64 + lane;
            float x = sx[n], y = sy[n], z = sz[n];
            float dst2 = f_add(f_add(f_mul(x,x), f_mul(y,y)), f_mul(z,z));
            float dot  = f_add(f_add(f_mul(cx,x), f_mul(cy,y)), f_mul(cz,z));
            d[j] = f_sub(f_add(src2, dst2), f_mul(2.0f, dot));
        }
        int myg  = 0;
        int prev = -1;
        for (int t = 0; t < 32; ++t) {
            float bv = INF_F; int bi = 0x7fffffff;
            #pragma unroll
            for (int j = 0; j < 64; ++j) {
                int n = j * 64 + lane;
                if (n == prev) d[j] = INF_F;
                float v = d[j];
                if (v < bv) { bv = v; bi = n; }
            }
            #pragma unroll
            for (int m = 1; m < 64; m <<= 1) {
                float ov = __shfl_xor(bv, m);
                int   oi = __shfl_xor(bi, m);
                if (ov < bv || (ov == bv && oi < bi)) { bv = ov; bi = oi; }
            }
            if (lane == t) myg = bi;
            prev = bi;
        }
        if (lane < 32) idxbuf[sl][lane] = myg;
    }
    __syncthreads();

    const int k   = tid & 31;
    const int sl2 = tid >> 5;
    const int s   = s_base + sl2;
    const int n   = idxbuf[sl2][k];

    const float cx = cent[sl2][0], cy = cent[sl2][1], cz = cent[sl2][2];
    float h0[9];
    h0[0] = sx[n] - cx;
    h0[1] = sy[n] - cy;
    h0[2] = sz[n] - cz;
    const float* pp = points + ((size_t)b * 4096 + n) * 6;
    #pragma unroll
    for (int c = 0; c < 6; ++c) h0[3 + c] = pp[c];

    float h1[64];
    #pragma unroll
    for (int o = 0; o < 64; ++o) {
        float acc = b0[o];
        #pragma unroll
        for (int c = 0; c < 9; ++c) acc = fmaf(h0[c], w0[o*9+c], acc);
        h1[o] = fmaxf(acc, 0.0f);
    }
    float h2[64];
    #pragma unroll
    for (int o = 0; o < 64; ++o) {
        float acc = b1[o];
        #pragma unroll
        for (int c = 0; c < 64; ++c) acc = fmaf(h1[c], w1[o*64+c], acc);
        h2[o] = fmaxf(acc, 0.0f);
    }
    float* outp = out_np + ((size_t)b * 1024 + s) * 128;
    for (int og = 0; og < 4; ++og) {
        float keep = 0.0f;
        for (int o2 = 0; o2 < 32; ++o2) {
            const int o = og * 32 + o2;
            float acc = b2[o];
            #pragma unroll
            for (int c = 0; c < 64; ++c) acc = fmaf(h2[c], w2[o*64+c], acc);
            float m = fmaxf(acc, 0.0f);
            #pragma unroll
            for (int mm = 1; mm < 32; mm <<= 1)
                m = fmaxf(m, __shfl_xor(m, mm));
            keep = (k == o2) ? m : keep;
        }
        outp[og * 32 + k] = keep;
    }
}

extern "C" void kernel_launch(void* const* d_in, const int* in_sizes, int n_in,
                              void* d_out, int out_size, void* d_ws, size_t ws_size,
                              hipStream_t stream) {
    const float* xyz           = (const float*)d_in[0];
    const float* points        = (const float*)d_in[1];
    const int*   farthest_init = (const int*)  d_in[2];
    const float* w0 = (const float*)d_in[3];
    const float* b0 = (const float*)d_in[4];
    const float* w1 = (const float*)d_in[5];
    const float* b1 = (const float*)d_in[6];
    const float* w2 = (const float*)d_in[7];
    const float* b2 = (const float*)d_in[8];

    float* out        = (float*)d_out;
    float* new_xyz    = out;                 // [8,1024,3]
    float* new_points = out + 8 * 1024 * 3;  // [8,1024,128]

    fps16_kernel<<<8, 1024, 0, stream>>>(xyz, farthest_init, new_xyz);

    if (ws_size >= (size_t)(8192 * 32 * sizeof(int))) {
        int* knn_idx = (int*)d_ws;
        knn_kernel<<<2048, 256, 0, stream>>>(xyz, new_xyz, knn_idx);
        mlp_kernel<<<1024, 256, 0, stream>>>(xyz, points, knn_idx,
                                             w0, b0, w1, b1, w2, b2,
                                             new_xyz, new_points);
    } else {
        knn_mlp_kernel<<<1024, 256, 0, stream>>>(xyz, points, w0, b0, w1, b1, w2, b2,
                                                 new_xyz, new_points);
    }
}

// Round 10
// 881.227 us; speedup vs baseline: 2.2202x; 1.6217x over previous
//
#include <hip/hip_runtime.h>

#define INF_F 3.402823466e+38f
typedef unsigned long long u64;
typedef __attribute__((ext_vector_type(2))) float f32x2;

__device__ __forceinline__ float f_add(float a, float b){ return __fadd_rn(a,b); }
__device__ __forceinline__ float f_sub(float a, float b){ return __fsub_rn(a,b); }
__device__ __forceinline__ float f_mul(float a, float b){ return __fmul_rn(a,b); }

// Packed fp32 (VOP3P) — same RN rounding as scalar, 2 elems/instr.
__device__ __forceinline__ f32x2 pk_add(f32x2 a, f32x2 b){ f32x2 d; asm("v_pk_add_f32 %0, %1, %2" : "=v"(d) : "v"(a), "v"(b)); return d; }
__device__ __forceinline__ f32x2 pk_mul(f32x2 a, f32x2 b){ f32x2 d; asm("v_pk_mul_f32 %0, %1, %2" : "=v"(d) : "v"(a), "v"(b)); return d; }
__device__ __forceinline__ f32x2 pk_fma(f32x2 a, f32x2 b, f32x2 c){ f32x2 d; asm("v_pk_fma_f32 %0, %1, %2, %3" : "=v"(d) : "v"(a), "v"(b), "v"(c)); return d; }

// DPP cross-lane (pure VALU). 0xB1=xor1, 0x4E=xor2, 0x141=xor4(8grp), 0x140=xor8(16grp)
template<int CTRL>
__device__ __forceinline__ double dpp_d(double x) {
    u64 u = (u64)__double_as_longlong(x);
    int lo = __builtin_amdgcn_update_dpp(0, (int)(unsigned)u,        CTRL, 0xF, 0xF, true);
    int hi = __builtin_amdgcn_update_dpp(0, (int)(unsigned)(u>>32), CTRL, 0xF, 0xF, true);
    return __longlong_as_double((long long)(((u64)(unsigned)hi << 32) | (unsigned)lo));
}
template<int CTRL>
__device__ __forceinline__ float dpp_f(float x) {
    int r = __builtin_amdgcn_update_dpp(0, __float_as_int(x), CTRL, 0xF, 0xF, true);
    return __int_as_float(r);
}
__device__ __forceinline__ float swz16_f(float x) {
    return __int_as_float(__builtin_amdgcn_ds_swizzle(__float_as_int(x), 0x401F));
}
__device__ __forceinline__ double readlane_d(double x, int l) {
    u64 u = (u64)__double_as_longlong(x);
    int lo = __builtin_amdgcn_readlane((int)(unsigned)u,        l);
    int hi = __builtin_amdgcn_readlane((int)(unsigned)(u>>32), l);
    return __longlong_as_double((long long)(((u64)(unsigned)hi << 32) | (unsigned)lo));
}
__device__ __forceinline__ unsigned key_lo(double k) {
    return (unsigned)((u64)__double_as_longlong(k) & 0xFFFFFFFFull);
}
__device__ __forceinline__ double pack_key(float nd, unsigned low) {
    return __longlong_as_double((long long)(((u64)__float_as_uint(nd) << 32) | (u64)low));
}

// wave-64 reduce of f64 keys -> all lanes (4 dpp stages + readlane tree)
__device__ __forceinline__ double wave_max_key(double k) {
    k = fmax(k, dpp_d<0xB1>(k));
    k = fmax(k, dpp_d<0x4E>(k));
    k = fmax(k, dpp_d<0x141>(k));
    k = fmax(k, dpp_d<0x140>(k));
    double a = readlane_d(k, 0),  b = readlane_d(k, 16);
    double c = readlane_d(k, 32), d = readlane_d(k, 48);
    return fmax(fmax(a, b), fmax(c, d));
}
__device__ __forceinline__ double wave_min_key(double k) {
    k = fmin(k, dpp_d<0xB1>(k));
    k = fmin(k, dpp_d<0x4E>(k));
    k = fmin(k, dpp_d<0x141>(k));
    k = fmin(k, dpp_d<0x140>(k));
    double a = readlane_d(k, 0),  b = readlane_d(k, 16);
    double c = readlane_d(k, 32), d = readlane_d(k, 48);
    return fmin(fmin(a, b), fmin(c, d));
}

// ---------------------------------------------------------------------------
// FPS, 8 waves (512 threads) per batch: the comm/update sweet spot.
// Cheap update datapath: pure-f32 distance min (pk ops + v_min_f32), per-
// thread value-only max tree, lowest-index-among-ties via cmp+min_u32, and
// ONE f64 key pack per thread per iteration (f64 max is half-rate — avoid it
// in the inner loop). Reduce: r7's proven skeleton (DPP f64 + readlane tree,
// 8 LDS slots, 1 barrier, fold, sp[far] b128 read).
// Key = (bits(vmax)<<32)|(4095-bestn): fmax == (value, lowest idx) == np.argmax.
// Key semantics identical to r5/r7 -> FPS indices bit-exact.
// ---------------------------------------------------------------------------
__global__ __launch_bounds__(512, 1) void fps8_kernel(
    const float* __restrict__ xyz, const int* __restrict__ farthest_init,
    float* __restrict__ out_new_xyz)
{
    const int b    = blockIdx.x;
    const int tid  = threadIdx.x;
    const int lane = tid & 63;
    const int wid  = tid >> 6;

    __shared__ float4 sp[4096];
    __shared__ int    hist[1024];
    __shared__ double red[2][8];

    const float* xb = xyz + (size_t)b * 4096 * 3;
    for (int n = tid; n < 4096; n += 512)
        sp[n] = make_float4(xb[n*3+0], xb[n*3+1], xb[n*3+2], 0.0f);
    __syncthreads();

    // 8 points/thread: n = j*512 + tid (j ascending == n ascending)
    f32x2 px[4], py[4], pz[4], d2a[4];
    #pragma unroll
    for (int jp = 0; jp < 4; ++jp) {
        const int n0 = (2*jp)*512 + tid, n1 = n0 + 512;
        float4 a = sp[n0], c = sp[n1];
        px[jp] = (f32x2){a.x, c.x};
        py[jp] = (f32x2){a.y, c.y};
        pz[jp] = (f32x2){a.z, c.z};
        d2a[jp] = (f32x2){1e10f, 1e10f};
    }

    int far = farthest_init[b];
    float4 cen = sp[far];
    float cx = cen.x, cy = cen.y, cz = cen.z;
    int p = 0;

    #pragma unroll 1
    for (int it = 0; it < 1024; ++it) {
        if (tid == 0) hist[it] = far;
        const f32x2 ncx = (f32x2){-cx, -cx};
        const f32x2 ncy = (f32x2){-cy, -cy};
        const f32x2 ncz = (f32x2){-cz, -cz};

        // pure-f32 distance update (exact RN, exact reference op order)
        float nd[8];
        #pragma unroll
        for (int jp = 0; jp < 4; ++jp) {
            f32x2 dx = pk_add(px[jp], ncx);          // x + (-c) == x - c exactly
            f32x2 dy = pk_add(py[jp], ncy);
            f32x2 dz = pk_add(pz[jp], ncz);
            // exact reference order: (dx^2 + dy^2) + dz^2, no FMA
            f32x2 d2 = pk_add(pk_add(pk_mul(dx,dx), pk_mul(dy,dy)), pk_mul(dz,dz));
            float a0 = fminf(d2a[jp][0], d2[0]);
            float a1 = fminf(d2a[jp][1], d2[1]);
            d2a[jp][0] = a0; d2a[jp][1] = a1;
            nd[2*jp+0] = a0;                          // n = (2jp)*512 + tid
            nd[2*jp+1] = a1;                          // n = (2jp+1)*512 + tid
        }
        // per-thread max value (compiler fuses to v_max3_f32)
        float vmax = fmaxf(fmaxf(fmaxf(nd[0], nd[1]), fmaxf(nd[2], nd[3])),
                           fmaxf(fmaxf(nd[4], nd[5]), fmaxf(nd[6], nd[7])));
        // lowest index among this thread's ties
        unsigned bestn = 0xFFFFFFFFu;
        #pragma unroll
        for (int j = 0; j < 8; ++j) {
            unsigned nj = (unsigned)(j*512 + tid);
            bestn = min(bestn, (nd[j] == vmax) ? nj : 0xFFFFFFFFu);
        }
        // ONE f64 key per thread; wave argmax; cross-wave via 8 slots
        double wkey = wave_max_key(pack_key(vmax, 4095u - bestn));
        if (lane == 0) red[p][wid] = wkey;
        __syncthreads();
        const double g = fmax(fmax(fmax(red[p][0], red[p][1]), fmax(red[p][2], red[p][3])),
                              fmax(fmax(red[p][4], red[p][5]), fmax(red[p][6], red[p][7])));
        far = 4095 - (int)key_lo(g);
        float4 cc = sp[far];                          // single ds_read_b128
        cx = cc.x; cy = cc.y; cz = cc.z;
        p ^= 1;   // double-buffered slots: 1 barrier per iteration
    }
    __syncthreads();
    #pragma unroll
    for (int q = 0; q < 2; ++q) {
        int s = q * 512 + tid;
        float4 cc = sp[hist[s]];
        float* o = out_new_xyz + ((size_t)b * 1024 + s) * 3;
        o[0] = cc.x; o[1] = cc.y; o[2] = cc.z;
    }
}

// ---------------------------------------------------------------------------
// Kernel 2: kNN top-32 (unchanged, known-good). One wave per centroid.
// ---------------------------------------------------------------------------
template<int G>
__device__ __forceinline__ double rebuild8(const double (&key)[64], double w) {
    const double DINF = __builtin_huge_val();
    double m = DINF;
    #pragma unroll
    for (int e = 0; e < 8; ++e) {
        double v = key[G*8+e];
        v = (v > w) ? v : DINF;
        m = fmin(m, v);
    }
    return m;
}

__global__ __launch_bounds__(256, 1) void knn_kernel(
    const float* __restrict__ xyz, const float* __restrict__ new_xyz,
    int* __restrict__ out_idx)
{
    const int tid  = threadIdx.x;
    const int lane = tid & 63;
    const int wid  = tid >> 6;
    const int blk  = blockIdx.x * 4 + wid;   // 0..8191 = b*1024 + s
    const int b    = blk >> 10;

    const float* xb = xyz + (size_t)b * 4096 * 3;
    const float* cp = new_xyz + (size_t)blk * 3;
    const float cx = cp[0], cy = cp[1], cz = cp[2];
    const float src2 = f_add(f_add(f_mul(cx,cx), f_mul(cy,cy)), f_mul(cz,cz));

    double key[64];
    #pragma unroll
    for (int j = 0; j < 64; ++j) {
        const int n = j * 64 + lane;
        const float* pt = xb + n * 3;
        float x = pt[0], y = pt[1], z = pt[2];
        float dst2 = f_add(f_add(f_mul(x,x), f_mul(y,y)), f_mul(z,z));
        float dot  = f_add(f_add(f_mul(cx,x), f_mul(cy,y)), f_mul(cz,z));
        float d = f_sub(f_add(src2, dst2), f_mul(2.0f, dot));   // exact reference form
        key[j] = __longlong_as_double((long long)(((u64)__float_as_uint(d) << 32) | (u64)(unsigned)n));
    }

    double gm[8];
    #pragma unroll
    for (int g = 0; g < 8; ++g) {
        double m = key[g*8];
        #pragma unroll
        for (int e = 1; e < 8; ++e) m = fmin(m, key[g*8+e]);
        gm[g] = m;
    }

    double w = -1.0;
    int myidx = 0;
    #pragma unroll 1
    for (int t = 0; t < 32; ++t) {
        double lm = fmin(fmin(fmin(gm[0], gm[1]), fmin(gm[2], gm[3])),
                         fmin(fmin(gm[4], gm[5]), fmin(gm[6], gm[7])));
        double gmin = wave_min_key(lm);
        int n = (int)(unsigned)((u64)__double_as_longlong(gmin) & 0xFFFFFFFFull);
        if (lane == t) myidx = n;
        w = gmin;
        const int gs = __builtin_amdgcn_readfirstlane(n >> 9);
        switch (gs) {
            case 0: gm[0] = rebuild8<0>(key, w); break;
            case 1: gm[1] = rebuild8<1>(key, w); break;
            case 2: gm[2] = rebuild8<2>(key, w); break;
            case 3: gm[3] = rebuild8<3>(key, w); break;
            case 4: gm[4] = rebuild8<4>(key, w); break;
            case 5: gm[5] = rebuild8<5>(key, w); break;
            case 6: gm[6] = rebuild8<6>(key, w); break;
            case 7: gm[7] = rebuild8<7>(key, w); break;
        }
    }
    if (lane < 32) out_idx[(size_t)blk * 32 + lane] = myidx;
}

// ---------------------------------------------------------------------------
// Kernel 3: 3-layer MLP + max-pool over K=32 (unchanged).
// ---------------------------------------------------------------------------
__global__ __launch_bounds__(256, 1) void mlp_kernel(
    const float* __restrict__ xyz, const float* __restrict__ points,
    const int* __restrict__ knn_idx,
    const float* __restrict__ w0, const float* __restrict__ b0,
    const float* __restrict__ w1, const float* __restrict__ b1,
    const float* __restrict__ w2, const float* __restrict__ b2,
    const float* __restrict__ new_xyz, float* __restrict__ out_np)
{
    const int tid = threadIdx.x;
    const int k   = tid & 31;
    const int gs  = blockIdx.x * 8 + (tid >> 5);   // 0..8191
    const int b   = gs >> 10;
    const int n   = knn_idx[(size_t)gs * 32 + k];

    const float cx = new_xyz[gs*3+0], cy = new_xyz[gs*3+1], cz = new_xyz[gs*3+2];
    const float* pxyz = xyz + ((size_t)b * 4096 + n) * 3;
    float h0[9];
    h0[0] = pxyz[0] - cx;
    h0[1] = pxyz[1] - cy;
    h0[2] = pxyz[2] - cz;
    const float* pp = points + ((size_t)b * 4096 + n) * 6;
    #pragma unroll
    for (int c = 0; c < 6; ++c) h0[3 + c] = pp[c];

    f32x2 h1p[32];
    #pragma unroll
    for (int o = 0; o < 64; o += 2) {
        float accA = b0[o], accB = b0[o+1];
        #pragma unroll
        for (int c = 0; c < 9; ++c) {
            accA = fmaf(h0[c], w0[o*9+c],     accA);
            accB = fmaf(h0[c], w0[(o+1)*9+c], accB);
        }
        h1p[o>>1] = (f32x2){fmaxf(accA, 0.0f), fmaxf(accB, 0.0f)};
    }

    const f32x2* w1v = (const f32x2*)w1;   // [64][32] pairs
    f32x2 h2p[32];
    #pragma unroll
    for (int o = 0; o < 64; o += 2) {
        f32x2 accA = (f32x2){b1[o],   0.0f};
        f32x2 accB = (f32x2){b1[o+1], 0.0f};
        #pragma unroll
        for (int i = 0; i < 32; ++i) {
            accA = pk_fma(h1p[i], w1v[o*32+i],     accA);
            accB = pk_fma(h1p[i], w1v[(o+1)*32+i], accB);
        }
        h2p[o>>1] = (f32x2){fmaxf(accA[0]+accA[1], 0.0f), fmaxf(accB[0]+accB[1], 0.0f)};
    }

    const f32x2* w2v = (const f32x2*)w2;   // [128][32] pairs
    float* outp = out_np + (size_t)gs * 128;
    for (int og = 0; og < 4; ++og) {
        float keep = 0.0f;
        for (int o2 = 0; o2 < 32; ++o2) {
            const int o = og * 32 + o2;
            f32x2 acc = (f32x2){b2[o], 0.0f};
            #pragma unroll
            for (int i = 0; i < 32; ++i) acc = pk_fma(h2p[i], w2v[o*32+i], acc);
            float m = fmaxf(acc[0] + acc[1], 0.0f);
            m = fmaxf(m, dpp_f<0xB1>(m));
            m = fmaxf(m, dpp_f<0x4E>(m));
            m = fmaxf(m, dpp_f<0x141>(m));
            m = fmaxf(m, dpp_f<0x140>(m));
            m = fmaxf(m, swz16_f(m));
            keep = (k == o2) ? m : keep;
        }
        outp[og * 32 + k] = keep;
    }
}

// ---------------------------------------------------------------------------
// Fallback (ws too small): fused kNN+MLP (known-correct).
// ---------------------------------------------------------------------------
__global__ __launch_bounds__(256) void knn_mlp_kernel(
    const float* __restrict__ xyz, const float* __restrict__ points,
    const float* __restrict__ w0, const float* __restrict__ b0,
    const float* __restrict__ w1, const float* __restrict__ b1,
    const float* __restrict__ w2, const float* __restrict__ b2,
    const float* __restrict__ new_xyz, float* __restrict__ out_np)
{
    const int blk    = blockIdx.x;
    const int b      = blk >> 7;
    const int s_base = (blk & 127) * 8;
    const int tid    = threadIdx.x;
    const int lane   = tid & 63;
    const int wid    = tid >> 6;

    __shared__ float sx[4096], sy[4096], sz[4096];
    __shared__ float cent[8][3];
    __shared__ int   idxbuf[8][32];

    const float* xb = xyz + (size_t)b * 4096 * 3;
    for (int n = tid; n < 4096; n += 256) {
        sx[n] = xb[n*3+0]; sy[n] = xb[n*3+1]; sz[n] = xb[n*3+2];
    }
    if (tid < 24) ((float*)cent)[tid] = new_xyz[((size_t)b * 1024 + s_base) * 3 + tid];
    __syncthreads();

    for (int si = 0; si < 2; ++si) {
        const int sl = wid * 2 + si;
        const float cx = cent[sl][0], cy = cent[sl][1], cz = cent[sl][2];
        const float src2 = f_add(f_add(f_mul(cx,cx), f_mul(cy,cy)), f_mul(cz,cz));
        float d[64];
        #pragma unroll
        for (int j = 0; j < 64; ++j) {
            int n = j * 64 + lane;
            float x = sx[n], y = sy[n], z = sz[n];
            float dst2 = f_add(f_add(f_mul(x,x), f_mul(y,y)), f_mul(z,z));
            float dot  = f_add(f_add(f_mul(cx,x), f_mul(cy,y)), f_mul(cz,z));
            d[j] = f_sub(f_add(src2, dst2), f_mul(2.0f, dot));
        }
        int myg  = 0;
        int prev = -1;
        for (int t = 0; t < 32; ++t) {
            float bv = INF_F; int bi = 0x7fffffff;
            #pragma unroll
            for (int j = 0; j < 64; ++j) {
                int n = j * 64 + lane;
                if (n == prev) d[j] = INF_F;
                float v = d[j];
                if (v < bv) { bv = v; bi = n; }
            }
            #pragma unroll
            for (int m = 1; m < 64; m <<= 1) {
                float ov = __shfl_xor(bv, m);
                int   oi = __shfl_xor(bi, m);
                if (ov < bv || (ov == bv && oi < bi)) { bv = ov; bi = oi; }
            }
            if (lane == t) myg = bi;
            prev = bi;
        }
        if (lane < 32) idxbuf[sl][lane] = myg;
    }
    __syncthreads();

    const int k   = tid & 31;
    const int sl2 = tid >> 5;
    const int s   = s_base + sl2;
    const int n   = idxbuf[sl2][k];

    const float cx = cent[sl2][0], cy = cent[sl2][1], cz = cent[sl2][2];
    float h0[9];
    h0[0] = sx[n] - cx;
    h0[1] = sy[n] - cy;
    h0[2] = sz[n] - cz;
    const float* pp = points + ((size_t)b * 4096 + n) * 6;
    #pragma unroll
    for (int c = 0; c < 6; ++c) h0[3 + c] = pp[c];

    float h1[64];
    #pragma unroll
    for (int o = 0; o < 64; ++o) {
        float acc = b0[o];
        #pragma unroll
        for (int c = 0; c < 9; ++c) acc = fmaf(h0[c], w0[o*9+c], acc);
        h1[o] = fmaxf(acc, 0.0f);
    }
    float h2[64];
    #pragma unroll
    for (int o = 0; o < 64; ++o) {
        float acc = b1[o];
        #pragma unroll
        for (int c = 0; c < 64; ++c) acc = fmaf(h1[c], w1[o*64+c], acc);
        h2[o] = fmaxf(acc, 0.0f);
    }
    float* outp = out_np + ((size_t)b * 1024 + s) * 128;
    for (int og = 0; og < 4; ++og) {
        float keep = 0.0f;
        for (int o2 = 0; o2 < 32; ++o2) {
            const int o = og * 32 + o2;
            float acc = b2[o];
            #pragma unroll
            for (int c = 0; c < 64; ++c) acc = fmaf(h2[c], w2[o*64+c], acc);
            float m = fmaxf(acc, 0.0f);
            #pragma unroll
            for (int mm = 1; mm < 32; mm <<= 1)
                m = fmaxf(m, __shfl_xor(m, mm));
            keep = (k == o2) ? m : keep;
        }
        outp[og * 32 + k] = keep;
    }
}

extern "C" void kernel_launch(void* const* d_in, const int* in_sizes, int n_in,
                              void* d_out, int out_size, void* d_ws, size_t ws_size,
                              hipStream_t stream) {
    const float* xyz           = (const float*)d_in[0];
    const float* points        = (const float*)d_in[1];
    const int*   farthest_init = (const int*)  d_in[2];
    const float* w0 = (const float*)d_in[3];
    const float* b0 = (const float*)d_in[4];
    const float* w1 = (const float*)d_in[5];
    const float* b1 = (const float*)d_in[6];
    const float* w2 = (const float*)d_in[7];
    const float* b2 = (const float*)d_in[8];

    float* out        = (float*)d_out;
    float* new_xyz    = out;                 // [8,1024,3]
    float* new_points = out + 8 * 1024 * 3;  // [8,1024,128]

    fps8_kernel<<<8, 512, 0, stream>>>(xyz, farthest_init, new_xyz);

    if (ws_size >= (size_t)(8192 * 32 * sizeof(int))) {
        int* knn_idx = (int*)d_ws;
        knn_kernel<<<2048, 256, 0, stream>>>(xyz, new_xyz, knn_idx);
        mlp_kernel<<<1024, 256, 0, stream>>>(xyz, points, knn_idx,
                                             w0, b0, w1, b1, w2, b2,
                                             new_xyz, new_points);
    } else {
        knn_mlp_kernel<<<1024, 256, 0, stream>>>(xyz, points, w0, b0, w1, b1, w2, b2,
                                                 new_xyz, new_points);
    }
}